// Round 1
// baseline (784.984 us; speedup 1.0000x reference)
//
#include <hip/hip_runtime.h>
#include <hip/hip_bf16.h>
#include <math.h>

// Problem constants: B=8, N=4096, M=4, A=32, P=4, W=16.  MA=128, PW=64.
// out[b,n,p,w] = relu( sum_c (adj[b,n,c] + I) * h[b,c,p,w] * rinv[b,n] ) + bias[p,w]
//   with h = einsum('bnma,mpaw->bnpw'), rinv = 1/rowsum(adj+I)

typedef __bf16 bf16_t;
typedef __bf16 bf16x8 __attribute__((ext_vector_type(8)));
typedef float f32x4 __attribute__((ext_vector_type(4)));

// -------------------------------------------------------------------------
// Kernel 1: per-node feature transform, h[b,n,pw], stored TRANSPOSED as
// Ht[b][pw][n] (bf16) so the GEMM's B-fragments are contiguous 16B loads.
// Block = 256 threads handles 64 consecutive nodes; wave wv handles p = wv
// (all 16 w's), lane = node. Weight rows are wave-uniform -> scalar loads.
// -------------------------------------------------------------------------
__global__ __launch_bounds__(256) void feat_kernel(
    const float* __restrict__ x, const float* __restrict__ weight,
    bf16_t* __restrict__ Ht)
{
  __shared__ float xs[64 * 129];  // stride 129: conflict-free lane*129+ma reads
  const int tid = threadIdx.x;
  const int node0 = blockIdx.x * 64;

  // stage x[node0..node0+63][0..127] into LDS (coalesced global float4 reads)
  const float* xb = x + (size_t)node0 * 128;
  #pragma unroll
  for (int it = 0; it < 8; ++it) {
    int g = (it * 256 + tid) * 4;      // 0..8191 step 4
    float4 v = *(const float4*)(xb + g);
    int nd = g >> 7, ma = g & 127;
    float* d = &xs[nd * 129 + ma];
    d[0] = v.x; d[1] = v.y; d[2] = v.z; d[3] = v.w;  // scalar: 129 stride not 16B-aligned
  }
  __syncthreads();

  const int lane = tid & 63;                                   // node within block
  const int p = __builtin_amdgcn_readfirstlane(tid >> 6);      // wave-uniform p

  float acc[16];
  #pragma unroll
  for (int w = 0; w < 16; ++w) acc[w] = 0.f;

  #pragma unroll 4
  for (int ma = 0; ma < 128; ++ma) {
    float xv = xs[lane * 129 + ma];
    // weight[m][p][a][w], m=ma>>5, a=ma&31 — uniform address -> s_load
    const float* wrow = weight + (((size_t)(ma >> 5) * 4 + p) * 32 + (ma & 31)) * 16;
    #pragma unroll
    for (int w = 0; w < 16; ++w) acc[w] += xv * wrow[w];
  }

  const int node_g = node0 + lane;
  const int b = node_g >> 12;      // 64 | 4096 so b uniform per block
  const int n = node_g & 4095;
  bf16_t* hbase = Ht + ((size_t)b * 64 + p * 16) * 4096 + n;
  #pragma unroll
  for (int w = 0; w < 16; ++w) hbase[(size_t)w * 4096] = (bf16_t)acc[w];  // coalesced across lanes
}

// -------------------------------------------------------------------------
// Kernel 2: S[b] = (adj[b] + I) @ H[b]  (4096x4096 @ 4096x64), then
// out = relu(S * rinv) + bias.  bf16 MFMA 16x16x32; A-fragments straight
// from global fp32 adj (8 contiguous floats/lane), converted in-register;
// rowsum fused into the A-load; B-fragments are 16B loads from Ht (L2-hot).
// Block = 4 waves x 16 rows = 64 rows; grid = 8 batches x 64 row-tiles.
// bid&7 = batch -> round-robin XCD dispatch keeps one batch's Ht per XCD L2.
// -------------------------------------------------------------------------
__global__ __launch_bounds__(256) void agg_kernel(
    const float* __restrict__ adj, const bf16_t* __restrict__ Ht,
    const float* __restrict__ bias, float* __restrict__ out)
{
  const int bid = blockIdx.x;
  const int b  = bid & 7;
  const int rt = bid >> 3;          // row tile 0..63
  const int tid  = threadIdx.x;
  const int wv   = tid >> 6;        // wave 0..3
  const int lane = tid & 63;
  const int l = lane & 15;          // MFMA A-row / B-col / C-col index
  const int q = lane >> 4;          // quad

  const int rowg = rt * 64 + wv * 16 + l;                       // global row n
  const float*  arow = adj + ((size_t)b * 4096 + rowg) * 4096;  // this lane's adj row
  const bf16_t* hb   = Ht + (size_t)b * 64 * 4096;

  f32x4 acc0 = {0.f,0.f,0.f,0.f}, acc1 = acc0, acc2 = acc0, acc3 = acc0;
  float rsum = 0.f;
  const int diag_k0 = rt * 64;      // the only k-tile containing this block's diagonal

  for (int k0 = 0; k0 < 4096; k0 += 64) {
    // ---- A tile: 2 half-tiles of K=32; lane reads 8 contiguous fp32 each ----
    float av[16];
    *(float4*)&av[0]  = *(const float4*)(arow + k0 + q * 8);
    *(float4*)&av[4]  = *(const float4*)(arow + k0 + q * 8 + 4);
    *(float4*)&av[8]  = *(const float4*)(arow + k0 + 32 + q * 8);
    *(float4*)&av[12] = *(const float4*)(arow + k0 + 32 + q * 8 + 4);

    if (k0 == diag_k0) {            // add identity: mx = adj + I
      int d  = rowg - k0;           // diagonal column offset within tile, [0,64)
      int e0 = d - q * 8;           // position within half 0
      if (e0 >= 0 && e0 < 8)  av[e0] += 1.f;
      int e1 = d - 32 - q * 8;      // position within half 1
      if (e1 >= 0 && e1 < 8)  av[8 + e1] += 1.f;
    }

    #pragma unroll
    for (int j = 0; j < 16; ++j) rsum += av[j];   // fused rowsum(mx) partial

    bf16x8 af0, af1;
    #pragma unroll
    for (int j = 0; j < 8; ++j) { af0[j] = (bf16_t)av[j]; af1[j] = (bf16_t)av[8 + j]; }

    // ---- B frags (Ht[pw][k], 16B contiguous per lane) + 8 MFMAs ----
    const bf16_t* hk = hb + (size_t)l * 4096 + k0 + q * 8;
    acc0 = __builtin_amdgcn_mfma_f32_16x16x32_bf16(af0, *(const bf16x8*)(hk),                 acc0, 0, 0, 0);
    acc0 = __builtin_amdgcn_mfma_f32_16x16x32_bf16(af1, *(const bf16x8*)(hk + 32),            acc0, 0, 0, 0);
    acc1 = __builtin_amdgcn_mfma_f32_16x16x32_bf16(af0, *(const bf16x8*)(hk + 16*4096),       acc1, 0, 0, 0);
    acc1 = __builtin_amdgcn_mfma_f32_16x16x32_bf16(af1, *(const bf16x8*)(hk + 16*4096 + 32),  acc1, 0, 0, 0);
    acc2 = __builtin_amdgcn_mfma_f32_16x16x32_bf16(af0, *(const bf16x8*)(hk + 32*4096),       acc2, 0, 0, 0);
    acc2 = __builtin_amdgcn_mfma_f32_16x16x32_bf16(af1, *(const bf16x8*)(hk + 32*4096 + 32),  acc2, 0, 0, 0);
    acc3 = __builtin_amdgcn_mfma_f32_16x16x32_bf16(af0, *(const bf16x8*)(hk + 48*4096),       acc3, 0, 0, 0);
    acc3 = __builtin_amdgcn_mfma_f32_16x16x32_bf16(af1, *(const bf16x8*)(hk + 48*4096 + 32),  acc3, 0, 0, 0);
  }

  // ---- rowsum across quads: lane(q,l) holds partial of row l ----
  rsum += __shfl_xor(rsum, 16);
  rsum += __shfl_xor(rsum, 32);
  float ri = 1.0f / rsum;
  if (isinf(ri)) ri = 0.f;          // reference: where(isinf(r_inv), 0)

  float bv0 = bias[l], bv1 = bias[16 + l], bv2 = bias[32 + l], bv3 = bias[48 + l];

  float* orow = out + ((size_t)b * 4096 + rt * 64 + wv * 16) * 64;
  #pragma unroll
  for (int i = 0; i < 4; ++i) {
    int row = q * 4 + i;                       // C/D layout: row = quad*4 + reg
    float riv = __shfl(ri, row);               // row's 1/rowsum (lane 'row' holds row l=row)
    float* o = orow + (size_t)row * 64 + l;
    o[0]  = fmaxf(acc0[i] * riv, 0.f) + bv0;
    o[16] = fmaxf(acc1[i] * riv, 0.f) + bv1;
    o[32] = fmaxf(acc2[i] * riv, 0.f) + bv2;
    o[48] = fmaxf(acc3[i] * riv, 0.f) + bv3;
  }
}

extern "C" void kernel_launch(void* const* d_in, const int* in_sizes, int n_in,
                              void* d_out, int out_size, void* d_ws, size_t ws_size,
                              hipStream_t stream) {
  const float* x      = (const float*)d_in[0];  // [8,4096,4,32]
  const float* adj    = (const float*)d_in[1];  // [8,4096,4096]
  const float* weight = (const float*)d_in[2];  // [4,4,32,16]
  const float* bias   = (const float*)d_in[3];  // [1,1,4,16]
  float* out = (float*)d_out;                   // [8,4096,4,16]

  bf16_t* Ht = (bf16_t*)d_ws;                   // [8][64][4096] bf16 = 4 MB

  feat_kernel<<<512, 256, 0, stream>>>(x, weight, Ht);
  agg_kernel<<<512, 256, 0, stream>>>(adj, Ht, bias, out);
}